// Round 2
// baseline (62.636 us; speedup 1.0000x reference)
//
#include <hip/hip_runtime.h>
#include <math.h>

// ---------------------------------------------------------------------------
// Net: conv2d(3->1,5x5,VALID) + bias -> xor_linear(784->128) -> step ->
//      xor_linear(128->64) -> step -> xor_linear(64->10) -> log_softmax
//
// xor_linear(X,W,b) = popcount(Xbits ^ Wbits) + b - in/2  (binary vectors)
// All pre-activations are exact small integers -> bit-exact thresholding.
//
// Structure: 8 samples per 256-thread block (grid = 1024 = 4 blocks/CU,
// co-resident). Per sample: reg-prefetch next sample's 12KB during conv
// (T14 async-stage), conv on 196 threads, layers 1-3 + softmax on wave 0
// only (ballot-packed bit vectors). 3 barriers/sample.
// ---------------------------------------------------------------------------

#define NW1  25   // 784 bits -> 25 u32 words
#define NW1P 28   // padded words per W1 row (16B multiple)
#define SPB  8    // samples per block

// Pack W1 (128x784) -> w1t[128][28] u32 row-major padded (pad words = 0),
//      W2 (64x128)  -> w2b[2][64]  u64,
//      W3 (10x64)   -> w3b[10]     u64.
__global__ void pack_weights(const float* __restrict__ W1,
                             const float* __restrict__ W2,
                             const float* __restrict__ W3,
                             unsigned* __restrict__ w1t,
                             unsigned long long* __restrict__ w2b,
                             unsigned long long* __restrict__ w3b) {
    int t = blockIdx.x * 256 + threadIdx.x;
    if (t < 128 * NW1P) {
        int i = t / NW1P, j = t % NW1P;
        unsigned v = 0;
        if (j < NW1) {
            int base = j * 32;
            #pragma unroll 8
            for (int b = 0; b < 32; ++b) {
                int col = base + b;
                if (col < 784 && W1[i * 784 + col] != 0.0f) v |= (1u << b);
            }
        }
        w1t[i * NW1P + j] = v;
    } else if (t < 128 * NW1P + 128) {
        int q = t - 128 * NW1P;
        int w = q >> 6, i = q & 63;
        unsigned long long v = 0;
        #pragma unroll 8
        for (int b = 0; b < 64; ++b)
            if (W2[i * 128 + w * 64 + b] != 0.0f) v |= (1ull << b);
        w2b[w * 64 + i] = v;
    } else if (t < 128 * NW1P + 128 + 10) {
        int i = t - (128 * NW1P + 128);
        unsigned long long v = 0;
        #pragma unroll 8
        for (int b = 0; b < 64; ++b)
            if (W3[i * 64 + b] != 0.0f) v |= (1ull << b);
        w3b[i] = v;
    }
}

__global__ __launch_bounds__(256, 4) void net_fused(
        const float* __restrict__ x,        // (B,3,32,32)
        const float* __restrict__ conv_w,   // (1,3,5,5)
        const float* __restrict__ conv_b,   // (1,)
        const float* __restrict__ b1,       // (128,)
        const float* __restrict__ b2,       // (64,)
        const float* __restrict__ b3,       // (10,)
        const unsigned* __restrict__ w1t,   // [128][28]
        const unsigned long long* __restrict__ w2b, // [2][64]
        const unsigned long long* __restrict__ w3b, // [10]
        float* __restrict__ out,            // (B,10)
        int B)
{
    // LDS: padded sample image (row stride 36 floats: 16B-aligned, spreads
    // banks), packed conv-output bits (padded to 28 words, pads stay 0).
    __shared__ __align__(16) float xs[3 * 32 * 36];      // 13824 B
    __shared__ __align__(16) unsigned xb32[NW1P];

    const int t = threadIdx.x;
    const long base_samp = (long)blockIdx.x * SPB;

    // LDS write target for this thread's 3 float4s (one per channel):
    // float idx fi = 4*(ch*256+t) -> ch, row = t>>3, col = (t&7)*4
    const int ldsf = (t >> 3) * 36 + (t & 7) * 4;

    const float cb = conv_b[0];

    // prefetch registers
    float4 r0, r1, r2;
    {
        const float4* xin = (const float4*)(x + base_samp * 3072);
        r0 = xin[t];
        r1 = xin[256 + t];
        r2 = xin[512 + t];
    }

    for (int s = 0; s < SPB; ++s) {
        const long samp = base_samp + s;
        if (samp >= B) break;                 // block-uniform

        // A: previous sample's conv LDS reads + wave0 xb32 reads are done
        __syncthreads();

        *(float4*)&xs[ldsf]            = r0;
        *(float4*)&xs[1152 + ldsf]     = r1;
        *(float4*)&xs[2304 + ldsf]     = r2;
        if (t < NW1P) xb32[t] = 0;

        // B: xs / xb32 ready
        __syncthreads();

        // issue next sample's loads (consumed after barrier A next iter;
        // conv + tail hide the HBM latency)
        if (s + 1 < SPB && samp + 1 < B) {
            const float4* nxt = (const float4*)(x + (samp + 1) * 3072);
            r0 = nxt[t];
            r1 = nxt[256 + t];
            r2 = nxt[512 + t];
        }

        // ---- conv: 196 threads, each a 1x4 output strip ----
        if (t < 196) {
            const int r = t / 7, c0 = (t % 7) * 4;
            float acc0 = cb, acc1 = cb, acc2 = cb, acc3 = cb;
            #pragma unroll
            for (int ch = 0; ch < 3; ++ch) {
                #pragma unroll
                for (int kr = 0; kr < 5; ++kr) {
                    const float* row = &xs[ch * 1152 + (r + kr) * 36 + c0];
                    float4 a = *(const float4*)row;
                    float4 bq = *(const float4*)(row + 4);
                    float in[8] = {a.x, a.y, a.z, a.w, bq.x, bq.y, bq.z, bq.w};
                    const float* wrow = &conv_w[ch * 25 + kr * 5]; // uniform -> SGPR
                    #pragma unroll
                    for (int kc = 0; kc < 5; ++kc) {
                        float w = wrow[kc];
                        acc0 += in[kc + 0] * w;
                        acc1 += in[kc + 1] * w;
                        acc2 += in[kc + 2] * w;
                        acc3 += in[kc + 3] * w;
                    }
                }
            }
            int idx = r * 28 + c0;            // bit index, multiple of 4
            unsigned nib = (unsigned)(acc0 != 0.0f)
                         | ((unsigned)(acc1 != 0.0f) << 1)
                         | ((unsigned)(acc2 != 0.0f) << 2)
                         | ((unsigned)(acc3 != 0.0f) << 3);
            atomicOr(&xb32[idx >> 5], nib << (idx & 31));
        }

        // C: xb32 complete
        __syncthreads();

        // ---- layers 1..3 + log_softmax: wave 0 only ----
        if (t < 64) {
            // layer 1: lane l computes h1 outputs l and l+64
            const uint4* xv4 = (const uint4*)xb32;          // 7 x uint4
            const uint4* wa  = (const uint4*)&w1t[t * NW1P];
            const uint4* wb  = (const uint4*)&w1t[(t + 64) * NW1P];
            int sa = 0, sb = 0;
            #pragma unroll
            for (int q = 0; q < 7; ++q) {
                uint4 xv = xv4[q];
                uint4 a  = wa[q];
                uint4 b  = wb[q];
                sa += __popc(xv.x ^ a.x) + __popc(xv.y ^ a.y)
                    + __popc(xv.z ^ a.z) + __popc(xv.w ^ a.w);
                sb += __popc(xv.x ^ b.x) + __popc(xv.y ^ b.y)
                    + __popc(xv.z ^ b.z) + __popc(xv.w ^ b.w);
            }
            float preA = (float)sa + b1[t]      - 392.0f;
            float preB = (float)sb + b1[t + 64] - 392.0f;
            unsigned long long h1lo = __ballot(preA >= 0.0f);
            unsigned long long h1hi = __ballot(preB >= 0.0f);

            // layer 2
            int s2 = __popcll(h1lo ^ w2b[t]) + __popcll(h1hi ^ w2b[64 + t]);
            float pre2 = (float)s2 + b2[t] - 64.0f;
            unsigned long long h2 = __ballot(pre2 >= 0.0f);

            // layer 3 + log_softmax (lanes 0..9 hold logits)
            float logit = -INFINITY;
            if (t < 10)
                logit = (float)__popcll(h2 ^ w3b[t]) + b3[t] - 32.0f;
            float m = logit;
            #pragma unroll
            for (int off = 8; off >= 1; off >>= 1)
                m = fmaxf(m, __shfl_xor(m, off, 16));
            float e = (t < 10) ? expf(logit - m) : 0.0f;
            float ssum = e;
            #pragma unroll
            for (int off = 8; off >= 1; off >>= 1)
                ssum += __shfl_xor(ssum, off, 16);
            if (t < 10)
                out[samp * 10 + t] = logit - m - logf(ssum);
        }
    }
}

extern "C" void kernel_launch(void* const* d_in, const int* in_sizes, int n_in,
                              void* d_out, int out_size, void* d_ws, size_t ws_size,
                              hipStream_t stream) {
    const float* x      = (const float*)d_in[0];
    const float* conv_w = (const float*)d_in[1];
    const float* conv_b = (const float*)d_in[2];
    const float* W1     = (const float*)d_in[3];
    const float* b1     = (const float*)d_in[4];
    const float* W2     = (const float*)d_in[5];
    const float* b2     = (const float*)d_in[6];
    const float* W3     = (const float*)d_in[7];
    const float* b3     = (const float*)d_in[8];
    float* out = (float*)d_out;

    const int B = in_sizes[0] / (3 * 32 * 32);

    // workspace layout
    unsigned* w1t            = (unsigned*)d_ws;                            // 128*28*4 = 14336 B
    unsigned long long* w2b  = (unsigned long long*)((char*)d_ws + 14336); // 1024 B
    unsigned long long* w3b  = (unsigned long long*)((char*)d_ws + 15360); // 80 B

    const int pack_threads = 128 * NW1P + 128 + 10;
    pack_weights<<<(pack_threads + 255) / 256, 256, 0, stream>>>(
        W1, W2, W3, w1t, w2b, w3b);

    const int grid = (B + SPB - 1) / SPB;
    net_fused<<<grid, 256, 0, stream>>>(x, conv_w, conv_b, b1, b2, b3,
                                        w1t, w2b, w3b, out, B);
}

// Round 3
// 52.920 us; speedup vs baseline: 1.1836x; 1.1836x over previous
//
#include <hip/hip_runtime.h>
#include <math.h>

// ---------------------------------------------------------------------------
// Net: conv2d(3->1,5x5,VALID) + bias -> xor_linear(784->128) -> step ->
//      xor_linear(128->64) -> step -> xor_linear(64->10) -> log_softmax
//
// xor_linear(X,W,b) = popcount(Xbits ^ Wbits) + b - in/2, where the FIRST
// layer binarizes with (conv_out + cb != 0)  [reference: Xb = (X != 0)],
// later layers with step() output (>= 0). All integer-exact.
//
// Structure: one wave = 2 samples (lane = half*32 + col). Column-threads
// march down 32 input rows with a 5-deep register line buffer; every input
// float is loaded once per lane (wave-load = 2 full 128B lines). ballot
// transposes col-bits -> row-bits; readlane/popcount/ballot run the binary
// tail per-wave. No LDS, no barriers, no atomics. 16 waves/CU.
// ---------------------------------------------------------------------------

#define NW1P 28   // padded u32 words per W1 row

__global__ void pack_weights(const float* __restrict__ W1,
                             const float* __restrict__ W2,
                             const float* __restrict__ W3,
                             unsigned* __restrict__ w1t,
                             unsigned long long* __restrict__ w2b,
                             unsigned long long* __restrict__ w3b) {
    int t = blockIdx.x * 256 + threadIdx.x;
    if (t < 128 * NW1P) {
        int i = t / NW1P, j = t % NW1P;
        unsigned v = 0;
        if (j < 25) {
            int base = j * 32;
            #pragma unroll 8
            for (int b = 0; b < 32; ++b) {
                int col = base + b;
                if (col < 784 && W1[i * 784 + col] != 0.0f) v |= (1u << b);
            }
        }
        w1t[i * NW1P + j] = v;
    } else if (t < 128 * NW1P + 128) {
        int q = t - 128 * NW1P;
        int w = q >> 6, i = q & 63;
        unsigned long long v = 0;
        #pragma unroll 8
        for (int b = 0; b < 64; ++b)
            if (W2[i * 128 + w * 64 + b] != 0.0f) v |= (1ull << b);
        w2b[w * 64 + i] = v;
    } else if (t < 128 * NW1P + 128 + 10) {
        int i = t - (128 * NW1P + 128);
        unsigned long long v = 0;
        #pragma unroll 8
        for (int b = 0; b < 64; ++b)
            if (W3[i * 64 + b] != 0.0f) v |= (1ull << b);
        w3b[i] = v;
    }
}

__global__ __launch_bounds__(256, 4) void net_all(
        const float* __restrict__ x,        // (B,3,32,32)
        const float* __restrict__ conv_w,   // (1,3,5,5)
        const float* __restrict__ conv_b,   // (1,)
        const float* __restrict__ b1,       // (128,)
        const float* __restrict__ b2,       // (64,)
        const float* __restrict__ b3,       // (10,)
        const unsigned* __restrict__ w1t,   // [128][28]
        const unsigned long long* __restrict__ w2b, // [2][64]
        const unsigned long long* __restrict__ w3b, // [10]
        float* __restrict__ out,            // (B,10)
        int B)
{
    const int tid  = threadIdx.x;
    const int lane = tid & 63;
    const int half = lane >> 5;
    const int c    = lane & 31;
    const int wid  = __builtin_amdgcn_readfirstlane(tid >> 6);
    const int pair = blockIdx.x * 4 + wid;            // wave-uniform
    const int npairs = (B + 1) >> 1;
    if (pair >= npairs) return;                        // wave-uniform exit

    const long  s    = (long)pair * 2 + half;
    const bool  sval = (s < (long)B);
    const float* __restrict__ base = x + (size_t)pair * 6144; // uniform

    // per-lane float-index offsets for the 15 (ch,k) load streams;
    // col rotated within the row so each wave-load spans exactly 2 lines
    int voff[15];
    #pragma unroll
    for (int ch = 0; ch < 3; ++ch)
        #pragma unroll
        for (int k = 0; k < 5; ++k)
            voff[ch * 5 + k] = (sval ? half : 0) * 3072 + ch * 1024 + ((c + k) & 31);

    const float cb = conv_b[0];
    float buf0[15], buf1[15], buf2[15];
    float A[5];                 // pending output-row accumulators (rot by orow%5)
    unsigned rowbits = 0;       // lane r (per half) ends holding row r's 28 bits

    #pragma unroll
    for (int i = 0; i < 15; ++i) buf0[i] = base[voff[i]];
    #pragma unroll
    for (int i = 0; i < 15; ++i) buf1[i] = base[voff[i] + 32];
    #pragma unroll
    for (int j = 0; j < 5; ++j) A[j] = cb;

    #pragma unroll
    for (int r = 0; r < 32; ++r) {
        float (&C)[15] = (r % 3 == 0) ? buf0 : (r % 3 == 1) ? buf1 : buf2;
        float (&N)[15] = ((r + 2) % 3 == 0) ? buf0
                        : ((r + 2) % 3 == 1) ? buf1 : buf2;
        // prefetch row r+2 (buffer freed at step r-1)
        if (r + 2 < 32) {
            #pragma unroll
            for (int i = 0; i < 15; ++i)
                N[i] = base[voff[i] + (r + 2) * 32];
        }
        // accumulate row r into the up-to-5 pending output rows
        #pragma unroll
        for (int kr = 0; kr < 5; ++kr) {
            const int orow = r - kr;
            if (orow >= 0 && orow < 28) {
                float a = A[orow % 5];
                #pragma unroll
                for (int ch = 0; ch < 3; ++ch)
                    #pragma unroll
                    for (int kc = 0; kc < 5; ++kc)
                        a = fmaf(C[ch * 5 + kc],
                                 conv_w[ch * 25 + kr * 5 + kc], a);
                A[orow % 5] = a;
            }
        }
        // retire output row r-4: binarize (!=0), transpose via ballot
        if (r >= 4) {
            const int orow = r - 4;
            float pre = A[orow % 5];
            unsigned long long bal = __ballot(pre != 0.0f);
            unsigned mb = (unsigned)(half ? (bal >> 32) : bal) & 0x0FFFFFFFu;
            if (c == orow) rowbits = mb;
            A[orow % 5] = cb;                 // recycle slot for orow+5
        }
    }

    // ---- pack 28x28 row-bits into 25 u32 words (lane c<25 owns word c) ----
    unsigned myword;
    {
        const int r0 = (c * 32) / 28;         // sh = 32c-28*r0 in {0,4,...,24}
        const int sh = c * 32 - r0 * 28;
        unsigned rb0 = __shfl(rowbits, half * 32 + r0);
        unsigned rb1 = __shfl(rowbits, half * 32 + r0 + 1); // lanes 28/29 hold 0
        unsigned long long v = (unsigned long long)rb0
                             | ((unsigned long long)rb1 << 28);
        myword = (c < 25) ? (unsigned)(v >> sh) : 0u;
    }

    // ---- binary tail, once per sample of the pair ----
    #pragma unroll
    for (int hs = 0; hs < 2; ++hs) {
        const long ss = (long)pair * 2 + hs;
        // layer 1: lane computes outputs `lane` and `lane+64`
        const uint4* wa = (const uint4*)(w1t + lane * NW1P);
        const uint4* wb = (const uint4*)(w1t + (lane + 64) * NW1P);
        int sa = 0, sb = 0;
        #pragma unroll
        for (int q = 0; q < 7; ++q) {
            uint4 a = wa[q], b = wb[q];
            unsigned x0 = __shfl(myword, hs * 32 + q * 4 + 0);
            unsigned x1 = __shfl(myword, hs * 32 + q * 4 + 1);
            unsigned x2 = __shfl(myword, hs * 32 + q * 4 + 2);
            unsigned x3 = __shfl(myword, hs * 32 + q * 4 + 3);
            sa += __popc(x0 ^ a.x) + __popc(x1 ^ a.y)
                + __popc(x2 ^ a.z) + __popc(x3 ^ a.w);
            sb += __popc(x0 ^ b.x) + __popc(x1 ^ b.y)
                + __popc(x2 ^ b.z) + __popc(x3 ^ b.w);
        }
        float preA = (float)sa + b1[lane]      - 392.0f;
        float preB = (float)sb + b1[lane + 64] - 392.0f;
        unsigned long long h1lo = __ballot(preA >= 0.0f);
        unsigned long long h1hi = __ballot(preB >= 0.0f);

        // layer 2
        int s2 = __popcll(h1lo ^ w2b[lane]) + __popcll(h1hi ^ w2b[64 + lane]);
        float pre2 = (float)s2 + b2[lane] - 64.0f;
        unsigned long long h2 = __ballot(pre2 >= 0.0f);

        // layer 3 + log_softmax (lanes 0..9)
        float logit = -INFINITY;
        if (lane < 10)
            logit = (float)__popcll(h2 ^ w3b[lane]) + b3[lane] - 32.0f;
        float m = logit;
        #pragma unroll
        for (int off = 8; off >= 1; off >>= 1)
            m = fmaxf(m, __shfl_xor(m, off, 16));
        float e = (lane < 10) ? expf(logit - m) : 0.0f;
        float ssum = e;
        #pragma unroll
        for (int off = 8; off >= 1; off >>= 1)
            ssum += __shfl_xor(ssum, off, 16);
        if (lane < 10 && ss < (long)B)
            out[ss * 10 + lane] = logit - m - logf(ssum);
    }
}

extern "C" void kernel_launch(void* const* d_in, const int* in_sizes, int n_in,
                              void* d_out, int out_size, void* d_ws, size_t ws_size,
                              hipStream_t stream) {
    const float* x      = (const float*)d_in[0];
    const float* conv_w = (const float*)d_in[1];
    const float* conv_b = (const float*)d_in[2];
    const float* W1     = (const float*)d_in[3];
    const float* b1     = (const float*)d_in[4];
    const float* W2     = (const float*)d_in[5];
    const float* b2     = (const float*)d_in[6];
    const float* W3     = (const float*)d_in[7];
    const float* b3     = (const float*)d_in[8];
    float* out = (float*)d_out;

    const int B = in_sizes[0] / (3 * 32 * 32);

    // workspace layout
    unsigned* w1t            = (unsigned*)d_ws;                            // 14336 B
    unsigned long long* w2b  = (unsigned long long*)((char*)d_ws + 14336); // 1024 B
    unsigned long long* w3b  = (unsigned long long*)((char*)d_ws + 15360); // 80 B

    const int pack_threads = 128 * NW1P + 128 + 10;
    pack_weights<<<(pack_threads + 255) / 256, 256, 0, stream>>>(
        W1, W2, W3, w1t, w2b, w3b);

    const int npairs = (B + 1) >> 1;
    const int grid = (npairs + 3) / 4;
    net_all<<<grid, 256, 0, stream>>>(x, conv_w, conv_b, b1, b2, b3,
                                      w1t, w2b, w3b, out, B);
}

// Round 4
// 44.002 us; speedup vs baseline: 1.4235x; 1.2027x over previous
//
#include <hip/hip_runtime.h>
#include <math.h>

// ---------------------------------------------------------------------------
// Net: conv2d(3->1,5x5,VALID) + bias -> xor_linear(784->128) -> step ->
//      xor_linear(128->64) -> step -> xor_linear(64->10) -> log_softmax
//
// xor_linear(X,W,b) = popcount(Xbits ^ Wbits) + b - in/2. First layer
// binarizes with (conv+bias != 0) [ref: Xb = (X != 0)], later layers with
// step() (>= 0). Integer-exact -> bit-exact thresholds.
//
// Structure: one wave = 2 samples (lane = half*32 + col). Lane loads its
// column ONCE per (ch,row) (3 loads/row-step); the 4 shifted conv operands
// come from ds_bpermute rotates within the 32-lane half (12/step). 5-row
// register line buffer = prefetch depth 5 (~900 cyc, covers HBM miss).
// ballot transposes col-bits -> row-bits; binary tail per-wave. No LDS,
// no barriers, no atomics, no spills (buffers 15 VGPR).
// ---------------------------------------------------------------------------

#define NW1P 28   // padded u32 words per W1 row

__global__ void pack_weights(const float* __restrict__ W1,
                             const float* __restrict__ W2,
                             const float* __restrict__ W3,
                             unsigned* __restrict__ w1t,
                             unsigned long long* __restrict__ w2b,
                             unsigned long long* __restrict__ w3b) {
    int t = blockIdx.x * 256 + threadIdx.x;
    if (t < 128 * NW1P) {
        int i = t / NW1P, j = t % NW1P;
        unsigned v = 0;
        if (j < 25) {
            int base = j * 32;
            #pragma unroll 8
            for (int b = 0; b < 32; ++b) {
                int col = base + b;
                if (col < 784 && W1[i * 784 + col] != 0.0f) v |= (1u << b);
            }
        }
        w1t[i * NW1P + j] = v;
    } else if (t < 128 * NW1P + 128) {
        int q = t - 128 * NW1P;
        int w = q >> 6, i = q & 63;
        unsigned long long v = 0;
        #pragma unroll 8
        for (int b = 0; b < 64; ++b)
            if (W2[i * 128 + w * 64 + b] != 0.0f) v |= (1ull << b);
        w2b[w * 64 + i] = v;
    } else if (t < 128 * NW1P + 128 + 10) {
        int i = t - (128 * NW1P + 128);
        unsigned long long v = 0;
        #pragma unroll 8
        for (int b = 0; b < 64; ++b)
            if (W3[i * 64 + b] != 0.0f) v |= (1ull << b);
        w3b[i] = v;
    }
}

__global__ __launch_bounds__(256, 4) void net_all(
        const float* __restrict__ x,        // (B,3,32,32)
        const float* __restrict__ conv_w,   // (1,3,5,5)
        const float* __restrict__ conv_b,   // (1,)
        const float* __restrict__ b1,       // (128,)
        const float* __restrict__ b2,       // (64,)
        const float* __restrict__ b3,       // (10,)
        const unsigned* __restrict__ w1t,   // [128][28]
        const unsigned long long* __restrict__ w2b, // [2][64]
        const unsigned long long* __restrict__ w3b, // [10]
        float* __restrict__ out,            // (B,10)
        int B)
{
    const int tid  = threadIdx.x;
    const int lane = tid & 63;
    const int half = lane >> 5;
    const int c    = lane & 31;
    const int wid  = __builtin_amdgcn_readfirstlane(tid >> 6);
    const int pair = blockIdx.x * 4 + wid;            // wave-uniform
    const int npairs = (B + 1) >> 1;
    if (pair >= npairs) return;                        // wave-uniform exit

    const long s    = (long)pair * 2 + half;
    const bool sval = (s < (long)B);
    const float* __restrict__ bp = x + (size_t)pair * 6144
                                     + (sval ? half * 3072 : 0) + c;

    // ds_bpermute byte-addresses: rotate-by-k within this 32-lane half
    int ba[4];
    #pragma unroll
    for (int k = 1; k <= 4; ++k)
        ba[k - 1] = (half * 32 + ((c + k) & 31)) * 4;

    const float cb = conv_b[0];

    float buf[5][3];            // 5-row line buffer (prefetch depth 5)
    float A[5];                 // pending output-row accumulators
    unsigned rowbits = 0;       // lane r (per half) ends holding row r's bits

    #pragma unroll
    for (int r = 0; r < 5; ++r) {
        buf[r][0] = bp[r * 32];
        buf[r][1] = bp[1024 + r * 32];
        buf[r][2] = bp[2048 + r * 32];
    }
    #pragma unroll
    for (int j = 0; j < 5; ++j) A[j] = cb;

    #pragma unroll
    for (int r = 0; r < 32; ++r) {
        // 15 shifted operands from 3 register values via bpermute rotates
        float v[3][5];
        #pragma unroll
        for (int ch = 0; ch < 3; ++ch) {
            float s0 = buf[r % 5][ch];
            v[ch][0] = s0;
            int iv = __builtin_bit_cast(int, s0);
            #pragma unroll
            for (int k = 1; k <= 4; ++k)
                v[ch][k] = __builtin_bit_cast(float,
                             __builtin_amdgcn_ds_bpermute(ba[k - 1], iv));
        }
        // prefetch row r+5 into the buffer freed this step
        if (r + 5 < 32) {
            buf[r % 5][0] = bp[(r + 5) * 32];
            buf[r % 5][1] = bp[1024 + (r + 5) * 32];
            buf[r % 5][2] = bp[2048 + (r + 5) * 32];
        }
        // accumulate row r into up-to-5 pending output rows
        #pragma unroll
        for (int kr = 0; kr < 5; ++kr) {
            const int orow = r - kr;
            if (orow >= 0 && orow < 28) {
                float a = A[orow % 5];
                #pragma unroll
                for (int ch = 0; ch < 3; ++ch)
                    #pragma unroll
                    for (int kc = 0; kc < 5; ++kc)
                        a = fmaf(v[ch][kc], conv_w[ch * 25 + kr * 5 + kc], a);
                A[orow % 5] = a;
            }
        }
        // retire output row r-4: binarize (!=0), transpose via ballot
        if (r >= 4) {
            const int orow = r - 4;
            float pre = A[orow % 5];
            unsigned long long bal = __ballot(pre != 0.0f);
            unsigned mb = (unsigned)(half ? (bal >> 32) : bal) & 0x0FFFFFFFu;
            if (c == orow) rowbits = mb;
            A[orow % 5] = cb;                 // recycle slot for orow+5
        }
    }

    // ---- pack 28x28 row-bits into 25 u32 words (lane c<25 owns word c) ----
    unsigned myword;
    {
        const int r0 = (c * 32) / 28;         // sh = 32c-28*r0 in {0,4,...,24}
        const int sh = c * 32 - r0 * 28;
        unsigned rb0 = __shfl(rowbits, half * 32 + r0);
        unsigned rb1 = __shfl(rowbits, half * 32 + r0 + 1); // lanes 28+ hold 0
        unsigned long long v = (unsigned long long)rb0
                             | ((unsigned long long)rb1 << 28);
        myword = (c < 25) ? (unsigned)(v >> sh) : 0u;
    }

    // ---- layer 1 for both samples with weights loaded once ----
    const uint4* wa = (const uint4*)(w1t + lane * NW1P);
    const uint4* wb = (const uint4*)(w1t + (lane + 64) * NW1P);
    int sa[2] = {0, 0}, sb[2] = {0, 0};
    #pragma unroll
    for (int q = 0; q < 7; ++q) {
        uint4 a = wa[q], b = wb[q];
        #pragma unroll
        for (int hs = 0; hs < 2; ++hs) {
            unsigned x0 = __shfl(myword, hs * 32 + q * 4 + 0);
            unsigned x1 = __shfl(myword, hs * 32 + q * 4 + 1);
            unsigned x2 = __shfl(myword, hs * 32 + q * 4 + 2);
            unsigned x3 = __shfl(myword, hs * 32 + q * 4 + 3);
            sa[hs] += __popc(x0 ^ a.x) + __popc(x1 ^ a.y)
                    + __popc(x2 ^ a.z) + __popc(x3 ^ a.w);
            sb[hs] += __popc(x0 ^ b.x) + __popc(x1 ^ b.y)
                    + __popc(x2 ^ b.z) + __popc(x3 ^ b.w);
        }
    }

    // ---- layers 2,3 + log_softmax per sample ----
    #pragma unroll
    for (int hs = 0; hs < 2; ++hs) {
        const long ss = (long)pair * 2 + hs;
        float preA = (float)sa[hs] + b1[lane]      - 392.0f;
        float preB = (float)sb[hs] + b1[lane + 64] - 392.0f;
        unsigned long long h1lo = __ballot(preA >= 0.0f);
        unsigned long long h1hi = __ballot(preB >= 0.0f);

        int s2 = __popcll(h1lo ^ w2b[lane]) + __popcll(h1hi ^ w2b[64 + lane]);
        float pre2 = (float)s2 + b2[lane] - 64.0f;
        unsigned long long h2 = __ballot(pre2 >= 0.0f);

        float logit = -INFINITY;
        if (lane < 10)
            logit = (float)__popcll(h2 ^ w3b[lane]) + b3[lane] - 32.0f;
        float m = logit;
        #pragma unroll
        for (int off = 8; off >= 1; off >>= 1)
            m = fmaxf(m, __shfl_xor(m, off, 16));
        float e = (lane < 10) ? expf(logit - m) : 0.0f;
        float ssum = e;
        #pragma unroll
        for (int off = 8; off >= 1; off >>= 1)
            ssum += __shfl_xor(ssum, off, 16);
        if (lane < 10 && ss < (long)B)
            out[ss * 10 + lane] = logit - m - logf(ssum);
    }
}

extern "C" void kernel_launch(void* const* d_in, const int* in_sizes, int n_in,
                              void* d_out, int out_size, void* d_ws, size_t ws_size,
                              hipStream_t stream) {
    const float* x      = (const float*)d_in[0];
    const float* conv_w = (const float*)d_in[1];
    const float* conv_b = (const float*)d_in[2];
    const float* W1     = (const float*)d_in[3];
    const float* b1     = (const float*)d_in[4];
    const float* W2     = (const float*)d_in[5];
    const float* b2     = (const float*)d_in[6];
    const float* W3     = (const float*)d_in[7];
    const float* b3     = (const float*)d_in[8];
    float* out = (float*)d_out;

    const int B = in_sizes[0] / (3 * 32 * 32);

    // workspace layout
    unsigned* w1t            = (unsigned*)d_ws;                            // 14336 B
    unsigned long long* w2b  = (unsigned long long*)((char*)d_ws + 14336); // 1024 B
    unsigned long long* w3b  = (unsigned long long*)((char*)d_ws + 15360); // 80 B

    const int pack_threads = 128 * NW1P + 128 + 10;
    pack_weights<<<(pack_threads + 255) / 256, 256, 0, stream>>>(
        W1, W2, W3, w1t, w2b, w3b);

    const int npairs = (B + 1) >> 1;
    const int grid = (npairs + 3) / 4;
    net_all<<<grid, 256, 0, stream>>>(x, conv_w, conv_b, b1, b2, b3,
                                      w1t, w2b, w3b, out, B);
}

// Round 5
// 42.338 us; speedup vs baseline: 1.4794x; 1.0393x over previous
//
#include <hip/hip_runtime.h>
#include <math.h>

// ---------------------------------------------------------------------------
// Net: conv2d(3->1,5x5,VALID) + bias -> xor_linear(784->128) -> step ->
//      xor_linear(128->64) -> step -> xor_linear(64->10) -> log_softmax
//
// xor_linear(X,W,b) = popcount(Xbits ^ Wbits) + b - in/2. First layer
// binarizes with (conv+bias != 0) [ref: Xb = (X != 0)], later layers with
// step() (>= 0). Integer-exact -> bit-exact thresholds.
//
// Structure: one wave = 2 samples (lane = half*32 + col). Lane loads its
// column ONCE per (ch,row) (3 dword loads/row-step); the 4 shifted conv
// operands come from chained DPP wave_shr:1 moves (pure VALU — zero DS
// traffic, no lgkmcnt). Cross-half leakage lands only in cols 28..31,
// which produce no output (masked). 5-row register line buffer = prefetch
// depth 5. ballot transposes col-bits -> row-bits; binary tail per-wave.
// No LDS, no barriers, no atomics.
// ---------------------------------------------------------------------------

#define NW1P 28   // padded u32 words per W1 row
#define DPP_WAVE_SHR1 0x138

__global__ void pack_weights(const float* __restrict__ W1,
                             const float* __restrict__ W2,
                             const float* __restrict__ W3,
                             unsigned* __restrict__ w1t,
                             unsigned long long* __restrict__ w2b,
                             unsigned long long* __restrict__ w3b) {
    int t = blockIdx.x * 256 + threadIdx.x;
    if (t < 128 * NW1P) {
        int i = t / NW1P, j = t % NW1P;
        unsigned v = 0;
        if (j < 25) {
            int base = j * 32;
            #pragma unroll 8
            for (int b = 0; b < 32; ++b) {
                int col = base + b;
                if (col < 784 && W1[i * 784 + col] != 0.0f) v |= (1u << b);
            }
        }
        w1t[i * NW1P + j] = v;
    } else if (t < 128 * NW1P + 128) {
        int q = t - 128 * NW1P;
        int w = q >> 6, i = q & 63;
        unsigned long long v = 0;
        #pragma unroll 8
        for (int b = 0; b < 64; ++b)
            if (W2[i * 128 + w * 64 + b] != 0.0f) v |= (1ull << b);
        w2b[w * 64 + i] = v;
    } else if (t < 128 * NW1P + 128 + 10) {
        int i = t - (128 * NW1P + 128);
        unsigned long long v = 0;
        #pragma unroll 8
        for (int b = 0; b < 64; ++b)
            if (W3[i * 64 + b] != 0.0f) v |= (1ull << b);
        w3b[i] = v;
    }
}

__global__ __launch_bounds__(256, 4) void net_all(
        const float* __restrict__ x,        // (B,3,32,32)
        const float* __restrict__ conv_w,   // (1,3,5,5)
        const float* __restrict__ conv_b,   // (1,)
        const float* __restrict__ b1,       // (128,)
        const float* __restrict__ b2,       // (64,)
        const float* __restrict__ b3,       // (10,)
        const unsigned* __restrict__ w1t,   // [128][28]
        const unsigned long long* __restrict__ w2b, // [2][64]
        const unsigned long long* __restrict__ w3b, // [10]
        float* __restrict__ out,            // (B,10)
        int B)
{
    const int tid  = threadIdx.x;
    const int lane = tid & 63;
    const int half = lane >> 5;
    const int c    = lane & 31;
    const int wid  = __builtin_amdgcn_readfirstlane(tid >> 6);
    const int pair = blockIdx.x * 4 + wid;            // wave-uniform
    const int npairs = (B + 1) >> 1;
    if (pair >= npairs) return;                        // wave-uniform exit

    const long s    = (long)pair * 2 + half;
    const bool sval = (s < (long)B);
    const float* __restrict__ bp = x + (size_t)pair * 6144
                                     + (sval ? half * 3072 : 0) + c;

    const float cb = conv_b[0];

    float buf[5][3];            // 5-row line buffer (prefetch depth 5)
    float A[5];                 // pending output-row accumulators
    unsigned rowbits = 0;       // lane r (per half) ends holding row r's bits

    #pragma unroll
    for (int r = 0; r < 5; ++r) {
        buf[r][0] = bp[r * 32];
        buf[r][1] = bp[1024 + r * 32];
        buf[r][2] = bp[2048 + r * 32];
    }
    #pragma unroll
    for (int j = 0; j < 5; ++j) A[j] = cb;

    #pragma unroll
    for (int r = 0; r < 32; ++r) {
        // 15 shifted operands from 3 register values via DPP wave_shr:1
        // chains (lane c picks up cols c+1..c+4; leakage only in cols>=28,
        // which produce no output).
        float v[3][5];
        #pragma unroll
        for (int ch = 0; ch < 3; ++ch) {
            float s0 = buf[r % 5][ch];
            v[ch][0] = s0;
            int iv = __builtin_bit_cast(int, s0);
            #pragma unroll
            for (int k = 1; k <= 4; ++k) {
                iv = __builtin_amdgcn_update_dpp(0, iv, DPP_WAVE_SHR1,
                                                 0xF, 0xF, true);
                v[ch][k] = __builtin_bit_cast(float, iv);
            }
        }
        // prefetch row r+5 into the buffer freed this step
        if (r + 5 < 32) {
            buf[r % 5][0] = bp[(r + 5) * 32];
            buf[r % 5][1] = bp[1024 + (r + 5) * 32];
            buf[r % 5][2] = bp[2048 + (r + 5) * 32];
        }
        // accumulate row r into up-to-5 pending output rows
        #pragma unroll
        for (int kr = 0; kr < 5; ++kr) {
            const int orow = r - kr;
            if (orow >= 0 && orow < 28) {
                float a = A[orow % 5];
                #pragma unroll
                for (int ch = 0; ch < 3; ++ch)
                    #pragma unroll
                    for (int kc = 0; kc < 5; ++kc)
                        a = fmaf(v[ch][kc], conv_w[ch * 25 + kr * 5 + kc], a);
                A[orow % 5] = a;
            }
        }
        // retire output row r-4: binarize (!=0), transpose via ballot
        if (r >= 4) {
            const int orow = r - 4;
            float pre = A[orow % 5];
            unsigned long long bal = __ballot(pre != 0.0f);
            unsigned mb = (unsigned)(half ? (bal >> 32) : bal) & 0x0FFFFFFFu;
            if (c == orow) rowbits = mb;
            A[orow % 5] = cb;                 // recycle slot for orow+5
        }
    }

    // ---- pack 28x28 row-bits into 25 u32 words (lane c<25 owns word c) ----
    unsigned myword;
    {
        const int r0 = (c * 32) / 28;         // sh = 32c-28*r0 in {0,4,...,24}
        const int sh = c * 32 - r0 * 28;
        unsigned rb0 = __shfl(rowbits, half * 32 + r0);
        unsigned rb1 = __shfl(rowbits, half * 32 + r0 + 1); // lanes 28+ hold 0
        unsigned long long v = (unsigned long long)rb0
                             | ((unsigned long long)rb1 << 28);
        myword = (c < 25) ? (unsigned)(v >> sh) : 0u;
    }

    // ---- layer 1 for both samples with weights loaded once ----
    const uint4* wa = (const uint4*)(w1t + lane * NW1P);
    const uint4* wb = (const uint4*)(w1t + (lane + 64) * NW1P);
    int sa[2] = {0, 0}, sb[2] = {0, 0};
    #pragma unroll
    for (int q = 0; q < 7; ++q) {
        uint4 a = wa[q], b = wb[q];
        #pragma unroll
        for (int hs = 0; hs < 2; ++hs) {
            unsigned x0 = __shfl(myword, hs * 32 + q * 4 + 0);
            unsigned x1 = __shfl(myword, hs * 32 + q * 4 + 1);
            unsigned x2 = __shfl(myword, hs * 32 + q * 4 + 2);
            unsigned x3 = __shfl(myword, hs * 32 + q * 4 + 3);
            sa[hs] += __popc(x0 ^ a.x) + __popc(x1 ^ a.y)
                    + __popc(x2 ^ a.z) + __popc(x3 ^ a.w);
            sb[hs] += __popc(x0 ^ b.x) + __popc(x1 ^ b.y)
                    + __popc(x2 ^ b.z) + __popc(x3 ^ b.w);
        }
    }

    // ---- layers 2,3 + log_softmax per sample ----
    #pragma unroll
    for (int hs = 0; hs < 2; ++hs) {
        const long ss = (long)pair * 2 + hs;
        float preA = (float)sa[hs] + b1[lane]      - 392.0f;
        float preB = (float)sb[hs] + b1[lane + 64] - 392.0f;
        unsigned long long h1lo = __ballot(preA >= 0.0f);
        unsigned long long h1hi = __ballot(preB >= 0.0f);

        int s2 = __popcll(h1lo ^ w2b[lane]) + __popcll(h1hi ^ w2b[64 + lane]);
        float pre2 = (float)s2 + b2[lane] - 64.0f;
        unsigned long long h2 = __ballot(pre2 >= 0.0f);

        float logit = -INFINITY;
        if (lane < 10)
            logit = (float)__popcll(h2 ^ w3b[lane]) + b3[lane] - 32.0f;
        float m = logit;
        #pragma unroll
        for (int off = 8; off >= 1; off >>= 1)
            m = fmaxf(m, __shfl_xor(m, off, 16));
        float e = (lane < 10) ? expf(logit - m) : 0.0f;
        float ssum = e;
        #pragma unroll
        for (int off = 8; off >= 1; off >>= 1)
            ssum += __shfl_xor(ssum, off, 16);
        if (lane < 10 && ss < (long)B)
            out[ss * 10 + lane] = logit - m - logf(ssum);
    }
}

extern "C" void kernel_launch(void* const* d_in, const int* in_sizes, int n_in,
                              void* d_out, int out_size, void* d_ws, size_t ws_size,
                              hipStream_t stream) {
    const float* x      = (const float*)d_in[0];
    const float* conv_w = (const float*)d_in[1];
    const float* conv_b = (const float*)d_in[2];
    const float* W1     = (const float*)d_in[3];
    const float* b1     = (const float*)d_in[4];
    const float* W2     = (const float*)d_in[5];
    const float* b2     = (const float*)d_in[6];
    const float* W3     = (const float*)d_in[7];
    const float* b3     = (const float*)d_in[8];
    float* out = (float*)d_out;

    const int B = in_sizes[0] / (3 * 32 * 32);

    // workspace layout
    unsigned* w1t            = (unsigned*)d_ws;                            // 14336 B
    unsigned long long* w2b  = (unsigned long long*)((char*)d_ws + 14336); // 1024 B
    unsigned long long* w3b  = (unsigned long long*)((char*)d_ws + 15360); // 80 B

    const int pack_threads = 128 * NW1P + 128 + 10;
    pack_weights<<<(pack_threads + 255) / 256, 256, 0, stream>>>(
        W1, W2, W3, w1t, w2b, w3b);

    const int npairs = (B + 1) >> 1;
    const int grid = (npairs + 3) / 4;
    net_all<<<grid, 256, 0, stream>>>(x, conv_w, conv_b, b1, b2, b3,
                                      w1t, w2b, w3b, out, B);
}